// Round 3
// baseline (823.663 us; speedup 1.0000x reference)
//
#include <hip/hip_runtime.h>
#include <math.h>

#define NE 150000

// type ids: SB=0 PQ=1 PV=2 NB=3
__constant__ int c_stype[15] = {2,0,0,2,3,1,0,1,3,1,2,3,2,1,3};
__constant__ int c_dtype[15] = {0,1,3,1,1,3,2,0,0,2,3,2,2,1,3};
__constant__ int c_slot[15]  = {0,0,0,1,2,1,0,1,2,1,2,2,3,3,3};
__constant__ int c_N[4]      = {4000,30000,15000,12000};
__constant__ int c_xoff[4]   = {0,4000,34000,49000};
__constant__ int c_cnt[4]    = {3,4,4,4};
__constant__ int c_aggoff[4] = {0,24000,264000,384000};
__constant__ int c_outoff[4] = {0,48000,528000,768000};
__constant__ int c_aggrows[4]= {24000,240000,120000,96000};
// per-type CSR offsets into gstart (stride N+1 per type)
__constant__ int c_toff2[15] = {0,4001,34002,46003,76004,106005,118006,133007,137008,141009,156010,168011,183012,198013,228014};

__device__ __forceinline__ float eluf(float x){ return x > 0.0f ? x : expm1f(x); }
__device__ __forceinline__ unsigned encf(float f){ unsigned u=__float_as_uint(f); return (u&0x80000000u)? ~u : (u|0x80000000u); }
__device__ __forceinline__ float decf(unsigned u){ return __uint_as_float((u&0x80000000u)? (u^0x80000000u) : ~u); }

// ---- build x = concat(x_nt, c_nt) for all 61000 nodes ----
__global__ __launch_bounds__(256) void k_build_x(
    const float* __restrict__ xSB, const float* __restrict__ cSB,
    const float* __restrict__ xPQ, const float* __restrict__ cPQ,
    const float* __restrict__ xPV, const float* __restrict__ cPV,
    const float* __restrict__ xNB, const float* __restrict__ cNB,
    float* __restrict__ xall){
  int n = blockIdx.x*256 + threadIdx.x;
  if (n >= 61000) return;
  const float *xp, *cp; int local;
  if (n < 4000)      { xp=xSB; cp=cSB; local=n; }
  else if (n < 34000){ xp=xPQ; cp=cPQ; local=n-4000; }
  else if (n < 49000){ xp=xPV; cp=cPV; local=n-34000; }
  else               { xp=xNB; cp=cNB; local=n-49000; }
  float4 a = ((const float4*)xp)[local];
  float4 b = ((const float4*)cp)[local];
  ((float4*)xall)[n*2+0] = a;
  ((float4*)xall)[n*2+1] = b;
}

// ---- derive per-conv small params (160 floats per conv) ----
__global__ __launch_bounds__(64) void k_params(
    const float* __restrict__ Wq, const float* __restrict__ bq,
    const float* __restrict__ Wk, const float* __restrict__ bk,
    const float* __restrict__ Wv, const float* __restrict__ bv,
    const float* __restrict__ We, const float* __restrict__ be,
    const float* __restrict__ Ws, const float* __restrict__ bs,
    float* __restrict__ par){
  const int c = blockIdx.x, tid = threadIdx.x;
  const float* wq = Wq + (size_t)c*1024;
  const float* wk = Wk + (size_t)c*1024;
  const float* wv = Wv + (size_t)c*1024;
  const float* ws = Ws + (size_t)c*1024;
  const float* we = We + (size_t)c*256;
  const float* vbq = bq + (size_t)c*128;
  const float* vbk = bk + (size_t)c*128;
  const float* vbv = bv + (size_t)c*128;
  const float* vbe = be + (size_t)c*128;
  const float* vbs = bs + (size_t)c*128;
  float* P = par + (size_t)c*160;
  { int fd = tid>>3, fs = tid&7; float s=0.f;
    for (int h=0;h<128;h++) s = fmaf(wq[fd*128+h], wk[fs*128+h], s);
    P[tid]=s; }
  const int grp = tid>>3, f = tid&7;
  if (grp==0){ float s=0.f; for(int h=0;h<128;h++) s=fmaf(wq[f*128+h],vbk[h],s); P[64+f]=s; }
  else if (grp==1){ float s=0.f; for(int h=0;h<128;h++) s=fmaf(wk[f*128+h],vbq[h],s); P[72+f]=s; }
  else if (grp==2){ float s=0.f; for(int h=0;h<128;h++) s=fmaf(wq[f*128+h],we[h],s); P[80+f]=s; }
  else if (grp==3){ float s=0.f; for(int h=0;h<128;h++) s=fmaf(wq[f*128+h],we[128+h],s); P[88+f]=s; }
  else if (grp==4){ float s=0.f; for(int h=0;h<128;h++) s=fmaf(wq[f*128+h],vbe[h],s); P[96+f]=s; }
  else if (grp==5){ float s0=0.f,s1=0.f; for(int h=0;h<64;h++){s0+=wv[f*128+h]; s1+=wv[f*128+64+h];} P[104+f]=s0; P[112+f]=s1; }
  else if (grp==6){ float s0=0.f,s1=0.f; for(int h=0;h<64;h++){s0+=ws[f*128+h]; s1+=ws[f*128+64+h];} P[120+f]=s0; P[128+f]=s1; }
  else {
    if (f==0){ float s=0.f; for(int h=0;h<128;h++) s=fmaf(vbq[h],vbk[h],s); P[136]=s;
               float a=0.f,b=0.f; for(int h=0;h<64;h++){a+=vbs[h]; b+=vbs[64+h];} P[148]=a; P[149]=b; }
    else if (f==1){ float s=0.f; for(int h=0;h<128;h++) s=fmaf(vbq[h],we[h],s); P[137]=s; }
    else if (f==2){ float s=0.f; for(int h=0;h<128;h++) s=fmaf(vbq[h],we[128+h],s); P[138]=s; }
    else if (f==3){ float s=0.f; for(int h=0;h<128;h++) s=fmaf(vbq[h],vbe[h],s); P[139]=s; }
    else if (f==4){ float a=0.f,b=0.f; for(int h=0;h<64;h++){a+=we[h]; b+=we[64+h];} P[140]=a; P[141]=b; }
    else if (f==5){ float a=0.f,b=0.f; for(int h=0;h<64;h++){a+=we[128+h]; b+=we[192+h];} P[142]=a; P[143]=b; }
    else if (f==6){ float a=0.f,b=0.f; for(int h=0;h<64;h++){a+=vbv[h]; b+=vbv[64+h];} P[144]=a; P[145]=b; }
    else          { float a=0.f,b=0.f; for(int h=0;h<64;h++){a+=vbe[h]; b+=vbe[64+h];} P[146]=a; P[147]=b; }
  }
}

// ---- CSR build + payload reorder: one block per edge type, LDS counting sort.
// Emits gstart (CSR row starts) and dst-sorted psrc (src index) / pea (edge attr)
// so the gather kernel streams sequential memory (no random eid indirection).
__global__ __launch_bounds__(1024) void k_csr(const int* __restrict__ eidx,
                                              const float* __restrict__ eattr,
                                              int* __restrict__ gstart,
                                              int* __restrict__ psrc,
                                              float2* __restrict__ pea){
  const int t = blockIdx.x;
  const int N = c_N[c_dtype[t]];
  const int o = c_toff2[t];
  const int tid = threadIdx.x;
  __shared__ int cnt[30000];
  __shared__ int wtot[16];
  for (int k=tid; k<N; k+=1024) cnt[k]=0;
  __syncthreads();
  const int* __restrict__ dstp = eidx + (size_t)(t*2+1)*NE;
  for (int e=tid; e<NE; e+=1024) atomicAdd(&cnt[dstp[e]], 1);
  __syncthreads();
  // block-wide exclusive scan over cnt[0..N)
  const int K = (N+1023)>>10;
  const int b0 = tid*K;
  int s = 0;
  for (int j=0;j<K;j++){ int k=b0+j; if (k<N) s += cnt[k]; }
  const int lane = tid & 63, wid = tid >> 6;
  int v = s;
  #pragma unroll
  for (int off=1; off<64; off<<=1){ int u = __shfl_up(v, off); if (lane>=off) v += u; }
  if (lane==63) wtot[wid]=v;
  __syncthreads();
  if (tid==0){ int r=0; for (int k=0;k<16;k++){ int tmp=wtot[k]; wtot[k]=r; r+=tmp; } }
  __syncthreads();
  int run = wtot[wid] + (v - s);
  for (int j=0;j<K;j++){ int k=b0+j; if (k<N){ int c0=cnt[k]; cnt[k]=run; run += c0; } }
  __syncthreads();
  for (int k=tid; k<N; k+=1024) gstart[o+k]=cnt[k];
  if (tid==0) gstart[o+N]=NE;
  __syncthreads();
  const int* __restrict__ srcp = eidx + (size_t)(t*2)*NE;
  const float2* __restrict__ ea2 = (const float2*)eattr + (size_t)t*NE;
  for (int e=tid; e<NE; e+=1024){
    int d = dstp[e];
    int pos = atomicAdd(&cnt[d], 1);
    psrc[(size_t)t*NE + pos] = srcp[e];
    pea [(size_t)t*NE + pos] = ea2[e];
  }
}

// ---- gather: per (type,node) walk CSR run ONCE, evaluate BOTH layers' convs.
// Fuses softmax, skip connection, and the global min/max reduction.
__global__ __launch_bounds__(256) void k_gather(
    const int* __restrict__ gstart, const int* __restrict__ psrc,
    const float2* __restrict__ pea,
    const float* __restrict__ xall, const float* __restrict__ par,
    const float* __restrict__ Wl, const float* __restrict__ bl,
    float* __restrict__ g, unsigned* __restrict__ mm){
  const int t = blockIdx.y;
  const int dt = c_dtype[t], st = c_stype[t];
  const int N = c_N[dt];
  if (blockIdx.x*256 >= N) return;
  __shared__ float sA[160], sB[160];
  __shared__ float wlb[192];
  __shared__ float smin[4], smax[4];
  const int tid = threadIdx.x;
  if (tid < 160){ sA[tid] = par[(size_t)t*160 + tid]; sB[tid] = par[(size_t)(15+t)*160 + tid]; }
  if (tid < 192) wlb[tid] = (tid<128)? Wl[tid] : bl[tid-128];
  __syncthreads();
  const int n = blockIdx.x*256 + tid;
  const bool valid = n < N;
  float lmin = 3.4e38f, lmax = -3.4e38f;
  if (valid){
    const float4* xdp = (const float4*)(xall + (size_t)(c_xoff[dt]+n)*8);
    float4 b0v = xdp[0], b1v = xdp[1];
    float xd[8] = {b0v.x,b0v.y,b0v.z,b0v.w,b1v.x,b1v.y,b1v.z,b1v.w};
    // per-node hoists for both convs
    float r2a[8], r2b[8];
    #pragma unroll
    for (int fs=0; fs<8; fs++){
      float a = sA[72+fs], b = sB[72+fs];
      #pragma unroll
      for (int fd=0; fd<8; fd++){ a = fmaf(xd[fd], sA[fd*8+fs], a); b = fmaf(xd[fd], sB[fd*8+fs], b); }
      r2a[fs]=a; r2b[fs]=b;
    }
    float t0a=sA[137], t1a=sA[138], tba=sA[139], u0a=sA[136];
    float t0b=sB[137], t1b=sB[138], tbb=sB[139], u0b=sB[136];
    #pragma unroll
    for (int f=0;f<8;f++){
      t0a = fmaf(xd[f], sA[80+f], t0a);  t0b = fmaf(xd[f], sB[80+f], t0b);
      t1a = fmaf(xd[f], sA[88+f], t1a);  t1b = fmaf(xd[f], sB[88+f], t1b);
      tba = fmaf(xd[f], sA[96+f], tba);  tbb = fmaf(xd[f], sB[96+f], tbb);
      u0a = fmaf(xd[f], sA[64+f], u0a);  u0b = fmaf(xd[f], sB[64+f], u0b);
    }
    const float accda = u0a + tba, accdb = u0b + tbb;
    const int o = c_toff2[t];
    const int js = gstart[o+n], je = gstart[o+n+1];
    const int* __restrict__ sp = psrc + (size_t)t*NE;
    const float2* __restrict__ ep = pea + (size_t)t*NE;
    float denA=0.f, n0A=0.f, n1A=0.f;
    float denB=0.f, n0B=0.f, n1B=0.f;
    for (int j=js; j<je; j++){
      const int src = sp[j];
      const float2 ea = ep[j];
      const float4* xsp = (const float4*)(xall + (size_t)(c_xoff[st]+src)*8);
      float4 a0v = xsp[0], a1v = xsp[1];
      float xs[8] = {a0v.x,a0v.y,a0v.z,a0v.w,a1v.x,a1v.y,a1v.z,a1v.w};
      float accA = accda, accB = accdb;
      float v0A = fmaf(ea.x, sA[140], fmaf(ea.y, sA[142], sA[144]+sA[146]));
      float v1A = fmaf(ea.x, sA[141], fmaf(ea.y, sA[143], sA[145]+sA[147]));
      float v0B = fmaf(ea.x, sB[140], fmaf(ea.y, sB[142], sB[144]+sB[146]));
      float v1B = fmaf(ea.x, sB[141], fmaf(ea.y, sB[143], sB[145]+sB[147]));
      #pragma unroll
      for (int f=0;f<8;f++){
        accA = fmaf(xs[f], r2a[f], accA);   accB = fmaf(xs[f], r2b[f], accB);
        v0A  = fmaf(xs[f], sA[104+f], v0A); v0B  = fmaf(xs[f], sB[104+f], v0B);
        v1A  = fmaf(xs[f], sA[112+f], v1A); v1B  = fmaf(xs[f], sB[112+f], v1B);
      }
      accA = fmaf(ea.x, t0a, fmaf(ea.y, t1a, accA));
      accB = fmaf(ea.x, t0b, fmaf(ea.y, t1b, accB));
      const float peA = __expf(accA * 0.08838834764831845f);
      const float peB = __expf(accB * 0.08838834764831845f);
      denA += peA; n0A = fmaf(peA, v0A, n0A); n1A = fmaf(peA, v1A, n1A);
      denB += peB; n0B = fmaf(peB, v0B, n0B); n1B = fmaf(peB, v1B, n1B);
    }
    const float invA = 1.0f/(denA + 1e-16f);
    const float invB = 1.0f/(denB + 1e-16f);
    float s0a = fmaf(n0A, invA, sA[148]), s1a = fmaf(n1A, invA, sA[149]);
    float s0b = fmaf(n0B, invB, sB[148]), s1b = fmaf(n1B, invB, sB[149]);
    #pragma unroll
    for (int f=0;f<8;f++){
      s0a = fmaf(xd[f], sA[120+f], s0a); s1a = fmaf(xd[f], sA[128+f], s1a);
      s0b = fmaf(xd[f], sB[120+f], s0b); s1b = fmaf(xd[f], sB[128+f], s1b);
    }
    const int baseA = c_aggoff[dt] + (0*c_cnt[dt] + c_slot[t])*N + n;
    const int baseB = c_aggoff[dt] + (1*c_cnt[dt] + c_slot[t])*N + n;
    g[(size_t)baseA*2+0]=s0a; g[(size_t)baseA*2+1]=s1a;
    g[(size_t)baseB*2+0]=s0b; g[(size_t)baseB*2+1]=s1b;
    #pragma unroll
    for (int h=0;h<64;h++){
      float za = fmaf(s0a, wlb[h], fmaf(s1a, wlb[64+h], wlb[128+h]));
      float zb = fmaf(s0b, wlb[h], fmaf(s1b, wlb[64+h], wlb[128+h]));
      lmin = fminf(lmin, fminf(za,zb)); lmax = fmaxf(lmax, fmaxf(za,zb));
    }
  }
  #pragma unroll
  for (int m=32;m>=1;m>>=1){
    lmin = fminf(lmin, __shfl_xor(lmin,m));
    lmax = fmaxf(lmax, __shfl_xor(lmax,m));
  }
  const int wv = tid>>6;
  if ((tid&63)==0){ smin[wv]=lmin; smax[wv]=lmax; }
  __syncthreads();
  if (tid==0){
    float mn = fminf(fminf(smin[0],smin[1]), fminf(smin[2],smin[3]));
    float mx = fmaxf(fmaxf(smax[0],smax[1]), fmaxf(smax[2],smax[3]));
    atomicMin(&mm[0], encf(mn));
    atomicMax(&mm[1], encf(mx));
  }
}

// ---- final: wave handles 32 rows; Wfc column resident in VGPRs, amortized ----
__global__ __launch_bounds__(256) void k_final(
    const float* __restrict__ g, const unsigned* __restrict__ mm,
    const float* __restrict__ Wl, const float* __restrict__ bl,
    const float* __restrict__ Wfc, const float* __restrict__ bfc,
    const float* __restrict__ Wl2, const float* __restrict__ bl2,
    float* __restrict__ out){
  const int bid = blockIdx.x;
  int nt, bo;
  if (bid < 188)       { nt=0; bo=0; }
  else if (bid < 2063) { nt=1; bo=188; }
  else if (bid < 3001) { nt=2; bo=2063; }
  else                 { nt=3; bo=3001; }
  const int w = threadIdx.x>>6, lane = threadIdx.x&63;
  const int R = c_aggrows[nt];
  const int r0 = (bid-bo)*128 + w*32;
  if (r0 >= R) return;  // wave-uniform, no barriers below
  const float wl0 = Wl[lane], wl1 = Wl[64+lane], blv = bl[lane];
  const float bfcv = bfc[nt*64+lane];
  const float wl20 = Wl2[lane], wl21 = Wl2[64+lane], bl2v = bl2[lane];
  float wfcr[64];
  const float* W = Wfc + (size_t)nt*4096;
  #pragma unroll
  for (int h=0;h<64;h++) wfcr[h] = W[h*64 + lane];
  const float zmin = decf(mm[0]), zmax = decf(mm[1]);
  const float rmin = 0.1f*eluf(zmin);
  const float rmax = 0.9f + 0.1f*eluf(zmax);
  const float s2 = 2.0f/(rmax - rmin + 1e-5f);
  const int nrows = min(32, R - r0);
  float gx=0.f, gy=0.f;
  if (lane < nrows){
    const float2 gv = ((const float2*)g)[c_aggoff[nt] + r0 + lane];
    gx = gv.x; gy = gv.y;
  }
  for (int r=0; r<nrows; r++){
    const float g0 = __uint_as_float(__builtin_amdgcn_readlane(__float_as_uint(gx), r));
    const float g1 = __uint_as_float(__builtin_amdgcn_readlane(__float_as_uint(gy), r));
    const float z = fmaf(g0, wl0, fmaf(g1, wl1, blv));
    const float nrm = fmaf(eluf(z) - rmin, s2, -1.0f);
    float acc = bfcv;
    #pragma unroll
    for (int h=0;h<64;h++){
      float nh = __uint_as_float(__builtin_amdgcn_readlane(__float_as_uint(nrm), h));
      acc = fmaf(nh, wfcr[h], acc);
    }
    float b = eluf(acc);
    float sgm = b;
    sgm += __shfl_xor(sgm,16);
    sgm += __shfl_xor(sgm,8);
    sgm += __shfl_xor(sgm,4);
    sgm += __shfl_xor(sgm,2);
    sgm += __shfl_xor(sgm,1);
    const float h0 = __uint_as_float(__builtin_amdgcn_readlane(__float_as_uint(sgm),0));
    const float h1 = __uint_as_float(__builtin_amdgcn_readlane(__float_as_uint(sgm),32));
    const float f = eluf(fmaf(h0, wl20, fmaf(h1, wl21, bl2v)));
    const size_t orow = (size_t)c_outoff[nt] + r0 + r;
    out[orow*64 + lane] = f;
    out[(orow + (size_t)R)*64 + lane] = f;
  }
}

extern "C" void kernel_launch(void* const* d_in, const int* in_sizes, int n_in,
                              void* d_out, int out_size, void* d_ws, size_t ws_size,
                              hipStream_t stream) {
  const float* xSB = (const float*)d_in[0];
  const float* cSB = (const float*)d_in[1];
  const float* xPQ = (const float*)d_in[2];
  const float* cPQ = (const float*)d_in[3];
  const float* xPV = (const float*)d_in[4];
  const float* cPV = (const float*)d_in[5];
  const float* xNB = (const float*)d_in[6];
  const float* cNB = (const float*)d_in[7];
  const int*   eidx = (const int*)d_in[8];
  const float* eattr= (const float*)d_in[9];
  const float* Wq = (const float*)d_in[10];
  const float* bq = (const float*)d_in[11];
  const float* Wk = (const float*)d_in[12];
  const float* bk = (const float*)d_in[13];
  const float* Wv = (const float*)d_in[14];
  const float* bv = (const float*)d_in[15];
  const float* We = (const float*)d_in[16];
  const float* be = (const float*)d_in[17];
  const float* Ws = (const float*)d_in[18];
  const float* bs = (const float*)d_in[19];
  const float* Wl = (const float*)d_in[20];
  const float* bl = (const float*)d_in[21];
  const float* Wfc= (const float*)d_in[22];
  const float* bfc= (const float*)d_in[23];
  const float* Wl2= (const float*)d_in[24];
  const float* bl2= (const float*)d_in[25];

  float* ws   = (float*)d_ws;
  float* xall   = ws + 0;              // 488000 f
  float* par    = ws + 488000;         // 4800 f
  int*   gstart = (int*)(ws + 492800); // 240015 i
  float* g      = ws + 732816;         // 960000 f
  int*   psrc   = (int*)(ws + 1692816);// 2250000 i
  float2* pea   = (float2*)(ws + 3942816); // 2250000 float2 (8B-aligned: even offset)
  unsigned* mm  = (unsigned*)(ws + 8442816); // 2

  hipMemsetAsync(mm,   0xFF, 4, stream);  // encoded min identity
  hipMemsetAsync(mm+1, 0x00, 4, stream);  // encoded max identity

  k_build_x<<<(61000+255)/256, 256, 0, stream>>>(xSB,cSB,xPQ,cPQ,xPV,cPV,xNB,cNB, xall);
  k_params<<<30, 64, 0, stream>>>(Wq,bq,Wk,bk,Wv,bv,We,be,Ws,bs, par);
  k_csr<<<15, 1024, 0, stream>>>(eidx, eattr, gstart, psrc, pea);
  dim3 gg((30000+255)/256, 15);
  k_gather<<<gg, 256, 0, stream>>>(gstart, psrc, pea, xall, par, Wl, bl, g, mm);
  k_final<<<3751, 256, 0, stream>>>(g, mm, Wl, bl, Wfc, bfc, Wl2, bl2, (float*)d_out);
}

// Round 4
// 587.649 us; speedup vs baseline: 1.4016x; 1.4016x over previous
//
#include <hip/hip_runtime.h>
#include <math.h>

#define NE 150000

// type ids: SB=0 PQ=1 PV=2 NB=3
__constant__ int c_stype[15] = {2,0,0,2,3,1,0,1,3,1,2,3,2,1,3};
__constant__ int c_dtype[15] = {0,1,3,1,1,3,2,0,0,2,3,2,2,1,3};
__constant__ int c_slot[15]  = {0,0,0,1,2,1,0,1,2,1,2,2,3,3,3};
__constant__ int c_N[4]      = {4000,30000,15000,12000};
__constant__ int c_xoff[4]   = {0,4000,34000,49000};
__constant__ int c_cnt[4]    = {3,4,4,4};
__constant__ int c_aggoff[4] = {0,24000,264000,384000};
__constant__ int c_outoff[4] = {0,48000,528000,768000};
__constant__ int c_aggrows[4]= {24000,240000,120000,96000};
// block -> (type, dst-tile) prefix: tiles per type = ceil(N[dtype]/1024)
__constant__ int c_tprefix[16] = {0,4,34,46,76,106,118,133,137,141,156,168,183,198,228,240};

__device__ __forceinline__ float eluf(float x){ return x > 0.0f ? x : expm1f(x); }
__device__ __forceinline__ unsigned encf(float f){ unsigned u=__float_as_uint(f); return (u&0x80000000u)? ~u : (u|0x80000000u); }
__device__ __forceinline__ float decf(unsigned u){ return __uint_as_float((u&0x80000000u)? (u^0x80000000u) : ~u); }

// ---- build x = concat(x_nt, c_nt) for all 61000 nodes ----
__global__ __launch_bounds__(256) void k_build_x(
    const float* __restrict__ xSB, const float* __restrict__ cSB,
    const float* __restrict__ xPQ, const float* __restrict__ cPQ,
    const float* __restrict__ xPV, const float* __restrict__ cPV,
    const float* __restrict__ xNB, const float* __restrict__ cNB,
    float* __restrict__ xall){
  int n = blockIdx.x*256 + threadIdx.x;
  if (n >= 61000) return;
  const float *xp, *cp; int local;
  if (n < 4000)      { xp=xSB; cp=cSB; local=n; }
  else if (n < 34000){ xp=xPQ; cp=cPQ; local=n-4000; }
  else if (n < 49000){ xp=xPV; cp=cPV; local=n-34000; }
  else               { xp=xNB; cp=cNB; local=n-49000; }
  float4 a = ((const float4*)xp)[local];
  float4 b = ((const float4*)cp)[local];
  ((float4*)xall)[n*2+0] = a;
  ((float4*)xall)[n*2+1] = b;
}

// ---- derive per-conv small params (160 floats per conv) ----
__global__ __launch_bounds__(64) void k_params(
    const float* __restrict__ Wq, const float* __restrict__ bq,
    const float* __restrict__ Wk, const float* __restrict__ bk,
    const float* __restrict__ Wv, const float* __restrict__ bv,
    const float* __restrict__ We, const float* __restrict__ be,
    const float* __restrict__ Ws, const float* __restrict__ bs,
    float* __restrict__ par){
  const int c = blockIdx.x, tid = threadIdx.x;
  const float* wq = Wq + (size_t)c*1024;
  const float* wk = Wk + (size_t)c*1024;
  const float* wv = Wv + (size_t)c*1024;
  const float* ws = Ws + (size_t)c*1024;
  const float* we = We + (size_t)c*256;
  const float* vbq = bq + (size_t)c*128;
  const float* vbk = bk + (size_t)c*128;
  const float* vbv = bv + (size_t)c*128;
  const float* vbe = be + (size_t)c*128;
  const float* vbs = bs + (size_t)c*128;
  float* P = par + (size_t)c*160;
  { int fd = tid>>3, fs = tid&7; float s=0.f;
    for (int h=0;h<128;h++) s = fmaf(wq[fd*128+h], wk[fs*128+h], s);
    P[tid]=s; }
  const int grp = tid>>3, f = tid&7;
  if (grp==0){ float s=0.f; for(int h=0;h<128;h++) s=fmaf(wq[f*128+h],vbk[h],s); P[64+f]=s; }
  else if (grp==1){ float s=0.f; for(int h=0;h<128;h++) s=fmaf(wk[f*128+h],vbq[h],s); P[72+f]=s; }
  else if (grp==2){ float s=0.f; for(int h=0;h<128;h++) s=fmaf(wq[f*128+h],we[h],s); P[80+f]=s; }
  else if (grp==3){ float s=0.f; for(int h=0;h<128;h++) s=fmaf(wq[f*128+h],we[128+h],s); P[88+f]=s; }
  else if (grp==4){ float s=0.f; for(int h=0;h<128;h++) s=fmaf(wq[f*128+h],vbe[h],s); P[96+f]=s; }
  else if (grp==5){ float s0=0.f,s1=0.f; for(int h=0;h<64;h++){s0+=wv[f*128+h]; s1+=wv[f*128+64+h];} P[104+f]=s0; P[112+f]=s1; }
  else if (grp==6){ float s0=0.f,s1=0.f; for(int h=0;h<64;h++){s0+=ws[f*128+h]; s1+=ws[f*128+64+h];} P[120+f]=s0; P[128+f]=s1; }
  else {
    if (f==0){ float s=0.f; for(int h=0;h<128;h++) s=fmaf(vbq[h],vbk[h],s); P[136]=s;
               float a=0.f,b=0.f; for(int h=0;h<64;h++){a+=vbs[h]; b+=vbs[64+h];} P[148]=a; P[149]=b; }
    else if (f==1){ float s=0.f; for(int h=0;h<128;h++) s=fmaf(vbq[h],we[h],s); P[137]=s; }
    else if (f==2){ float s=0.f; for(int h=0;h<128;h++) s=fmaf(vbq[h],we[128+h],s); P[138]=s; }
    else if (f==3){ float s=0.f; for(int h=0;h<128;h++) s=fmaf(vbq[h],vbe[h],s); P[139]=s; }
    else if (f==4){ float a=0.f,b=0.f; for(int h=0;h<64;h++){a+=we[h]; b+=we[64+h];} P[140]=a; P[141]=b; }
    else if (f==5){ float a=0.f,b=0.f; for(int h=0;h<64;h++){a+=we[128+h]; b+=we[192+h];} P[142]=a; P[143]=b; }
    else if (f==6){ float a=0.f,b=0.f; for(int h=0;h<64;h++){a+=vbv[h]; b+=vbv[64+h];} P[144]=a; P[145]=b; }
    else          { float a=0.f,b=0.f; for(int h=0;h<64;h++){a+=vbe[h]; b+=vbe[64+h];} P[146]=a; P[147]=b; }
  }
}

// ---- fused conv: one block per (type, 1024-dst-tile). Streams all edges of the
// type, accumulates softmax sums for in-tile dsts in LDS, finalizes g + minmax.
__global__ __launch_bounds__(1024) void k_fused(
    const int* __restrict__ eidx, const float* __restrict__ eattr,
    const float* __restrict__ xall, const float* __restrict__ par,
    const float* __restrict__ Wl, const float* __restrict__ bl,
    float* __restrict__ g, unsigned* __restrict__ mm){
  const int b = blockIdx.x;
  int t = 0;
  while (b >= c_tprefix[t+1]) ++t;
  const int tile = b - c_tprefix[t];
  const int dt = c_dtype[t], st = c_stype[t];
  const int N = c_N[dt];
  const int nbase = tile << 10;
  const int tileN = min(1024, N - nbase);
  const int tid = threadIdx.x;

  __shared__ float4 H4[6*1024];   // per-dst hoisted coeffs
  __shared__ float ACC[6*1024];   // denA,n0A,n1A,denB,n0B,n1B
  __shared__ float sA[160], sB[160], wlb[192];
  __shared__ float smin[16], smax[16];

  if (tid < 160){ sA[tid] = par[(size_t)t*160 + tid]; sB[tid] = par[(size_t)(15+t)*160 + tid]; }
  else if (tid < 352){ int u = tid-160; wlb[u] = (u<128)? Wl[u] : bl[u-128]; }
  for (int k=tid; k<6144; k+=1024) ACC[k]=0.f;
  __syncthreads();

  // hoist per-dst coefficients
  if (tid < tileN){
    const int n = nbase + tid;
    const float4* xdp = (const float4*)(xall + (size_t)(c_xoff[dt]+n)*8);
    float4 b0v = xdp[0], b1v = xdp[1];
    float xd[8] = {b0v.x,b0v.y,b0v.z,b0v.w,b1v.x,b1v.y,b1v.z,b1v.w};
    float r2a[8], r2b[8];
    #pragma unroll
    for (int fs=0; fs<8; fs++){
      float a = sA[72+fs], bb = sB[72+fs];
      #pragma unroll
      for (int fd=0; fd<8; fd++){ a = fmaf(xd[fd], sA[fd*8+fs], a); bb = fmaf(xd[fd], sB[fd*8+fs], bb); }
      r2a[fs]=a; r2b[fs]=bb;
    }
    float t0a=sA[137], t1a=sA[138], tba=sA[139], u0a=sA[136];
    float t0b=sB[137], t1b=sB[138], tbb=sB[139], u0b=sB[136];
    #pragma unroll
    for (int f=0;f<8;f++){
      t0a = fmaf(xd[f], sA[80+f], t0a);  t0b = fmaf(xd[f], sB[80+f], t0b);
      t1a = fmaf(xd[f], sA[88+f], t1a);  t1b = fmaf(xd[f], sB[88+f], t1b);
      tba = fmaf(xd[f], sA[96+f], tba);  tbb = fmaf(xd[f], sB[96+f], tbb);
      u0a = fmaf(xd[f], sA[64+f], u0a);  u0b = fmaf(xd[f], sB[64+f], u0b);
    }
    H4[tid]        = make_float4(r2a[0],r2a[1],r2a[2],r2a[3]);
    H4[1024+tid]   = make_float4(r2a[4],r2a[5],r2a[6],r2a[7]);
    H4[2048+tid]   = make_float4(r2b[0],r2b[1],r2b[2],r2b[3]);
    H4[3072+tid]   = make_float4(r2b[4],r2b[5],r2b[6],r2b[7]);
    H4[4096+tid]   = make_float4(t0a,t1a,u0a+tba,0.f);
    H4[5120+tid]   = make_float4(t0b,t1b,u0b+tbb,0.f);
  }
  // uniform per-conv value coefficients into registers
  float vA0[8], vA1[8], vB0[8], vB1[8];
  #pragma unroll
  for (int f=0;f<8;f++){ vA0[f]=sA[104+f]; vA1[f]=sA[112+f]; vB0[f]=sB[104+f]; vB1[f]=sB[112+f]; }
  const float cA0x=sA[140], cA0y=sA[142], cA0c=sA[144]+sA[146];
  const float cA1x=sA[141], cA1y=sA[143], cA1c=sA[145]+sA[147];
  const float cB0x=sB[140], cB0y=sB[142], cB0c=sB[144]+sB[146];
  const float cB1x=sB[141], cB1y=sB[143], cB1c=sB[145]+sB[147];
  __syncthreads();

  const int* __restrict__ dstp = eidx + (size_t)(t*2+1)*NE;
  const int* __restrict__ srcp = eidx + (size_t)(t*2)*NE;
  const float2* __restrict__ ea2 = (const float2*)eattr + (size_t)t*NE;
  const int xo = c_xoff[st];
  const float SCALE = 0.08838834764831845f;

  for (int e=tid; e<NE; e+=1024){
    const int d = dstp[e];
    const int src = srcp[e];
    const float2 ea = ea2[e];
    const int dl = d - nbase;
    if ((unsigned)dl < (unsigned)tileN){
      const float4* xsp = (const float4*)(xall + (size_t)(xo+src)*8);
      float4 a0v = xsp[0], a1v = xsp[1];
      float xs[8] = {a0v.x,a0v.y,a0v.z,a0v.w,a1v.x,a1v.y,a1v.z,a1v.w};
      float4 p0=H4[dl], p1=H4[1024+dl], p2=H4[2048+dl], p3=H4[3072+dl];
      float4 p4=H4[4096+dl], p5=H4[5120+dl];
      float accA = fmaf(ea.x, p4.x, fmaf(ea.y, p4.y, p4.z));
      float accB = fmaf(ea.x, p5.x, fmaf(ea.y, p5.y, p5.z));
      accA = fmaf(xs[0],p0.x, fmaf(xs[1],p0.y, fmaf(xs[2],p0.z, fmaf(xs[3],p0.w, accA))));
      accA = fmaf(xs[4],p1.x, fmaf(xs[5],p1.y, fmaf(xs[6],p1.z, fmaf(xs[7],p1.w, accA))));
      accB = fmaf(xs[0],p2.x, fmaf(xs[1],p2.y, fmaf(xs[2],p2.z, fmaf(xs[3],p2.w, accB))));
      accB = fmaf(xs[4],p3.x, fmaf(xs[5],p3.y, fmaf(xs[6],p3.z, fmaf(xs[7],p3.w, accB))));
      float v0A = fmaf(ea.x,cA0x, fmaf(ea.y,cA0y, cA0c));
      float v1A = fmaf(ea.x,cA1x, fmaf(ea.y,cA1y, cA1c));
      float v0B = fmaf(ea.x,cB0x, fmaf(ea.y,cB0y, cB0c));
      float v1B = fmaf(ea.x,cB1x, fmaf(ea.y,cB1y, cB1c));
      #pragma unroll
      for (int f=0;f<8;f++){
        v0A = fmaf(xs[f], vA0[f], v0A);
        v1A = fmaf(xs[f], vA1[f], v1A);
        v0B = fmaf(xs[f], vB0[f], v0B);
        v1B = fmaf(xs[f], vB1[f], v1B);
      }
      const float peA = __expf(accA * SCALE);
      const float peB = __expf(accB * SCALE);
      atomicAdd(&ACC[dl],      peA);
      atomicAdd(&ACC[1024+dl], peA*v0A);
      atomicAdd(&ACC[2048+dl], peA*v1A);
      atomicAdd(&ACC[3072+dl], peB);
      atomicAdd(&ACC[4096+dl], peB*v0B);
      atomicAdd(&ACC[5120+dl], peB*v1B);
    }
  }
  __syncthreads();

  // finalize: softmax divide + skip + g write + minmax
  float lmin = 3.4e38f, lmax = -3.4e38f;
  if (tid < tileN){
    const int n = nbase + tid;
    const float4* xdp = (const float4*)(xall + (size_t)(c_xoff[dt]+n)*8);
    float4 b0v = xdp[0], b1v = xdp[1];
    float xd[8] = {b0v.x,b0v.y,b0v.z,b0v.w,b1v.x,b1v.y,b1v.z,b1v.w};
    const float denA = ACC[tid],      n0A = ACC[1024+tid], n1A = ACC[2048+tid];
    const float denB = ACC[3072+tid], n0B = ACC[4096+tid], n1B = ACC[5120+tid];
    const float invA = 1.0f/(denA + 1e-16f);
    const float invB = 1.0f/(denB + 1e-16f);
    float s0a = fmaf(n0A, invA, sA[148]), s1a = fmaf(n1A, invA, sA[149]);
    float s0b = fmaf(n0B, invB, sB[148]), s1b = fmaf(n1B, invB, sB[149]);
    #pragma unroll
    for (int f=0;f<8;f++){
      s0a = fmaf(xd[f], sA[120+f], s0a); s1a = fmaf(xd[f], sA[128+f], s1a);
      s0b = fmaf(xd[f], sB[120+f], s0b); s1b = fmaf(xd[f], sB[128+f], s1b);
    }
    const int baseA = c_aggoff[dt] + (0*c_cnt[dt] + c_slot[t])*N + n;
    const int baseB = c_aggoff[dt] + (1*c_cnt[dt] + c_slot[t])*N + n;
    ((float2*)g)[baseA] = make_float2(s0a, s1a);
    ((float2*)g)[baseB] = make_float2(s0b, s1b);
    #pragma unroll
    for (int h=0;h<64;h++){
      float za = fmaf(s0a, wlb[h], fmaf(s1a, wlb[64+h], wlb[128+h]));
      float zb = fmaf(s0b, wlb[h], fmaf(s1b, wlb[64+h], wlb[128+h]));
      lmin = fminf(lmin, fminf(za,zb)); lmax = fmaxf(lmax, fmaxf(za,zb));
    }
  }
  #pragma unroll
  for (int m=32;m>=1;m>>=1){
    lmin = fminf(lmin, __shfl_xor(lmin,m));
    lmax = fmaxf(lmax, __shfl_xor(lmax,m));
  }
  const int wid = tid>>6;
  if ((tid&63)==0){ smin[wid]=lmin; smax[wid]=lmax; }
  __syncthreads();
  if (tid==0){
    float mn = smin[0], mx = smax[0];
    for (int k=1;k<16;k++){ mn = fminf(mn, smin[k]); mx = fmaxf(mx, smax[k]); }
    atomicMin(&mm[0], encf(mn));
    atomicMax(&mm[1], encf(mx));
  }
}

// ---- final: wave handles 32 rows; Wfc column resident in VGPRs, amortized ----
__global__ __launch_bounds__(256) void k_final(
    const float* __restrict__ g, const unsigned* __restrict__ mm,
    const float* __restrict__ Wl, const float* __restrict__ bl,
    const float* __restrict__ Wfc, const float* __restrict__ bfc,
    const float* __restrict__ Wl2, const float* __restrict__ bl2,
    float* __restrict__ out){
  const int bid = blockIdx.x;
  int nt, bo;
  if (bid < 188)       { nt=0; bo=0; }
  else if (bid < 2063) { nt=1; bo=188; }
  else if (bid < 3001) { nt=2; bo=2063; }
  else                 { nt=3; bo=3001; }
  const int w = threadIdx.x>>6, lane = threadIdx.x&63;
  const int R = c_aggrows[nt];
  const int r0 = (bid-bo)*128 + w*32;
  if (r0 >= R) return;  // wave-uniform, no barriers below
  const float wl0 = Wl[lane], wl1 = Wl[64+lane], blv = bl[lane];
  const float bfcv = bfc[nt*64+lane];
  const float wl20 = Wl2[lane], wl21 = Wl2[64+lane], bl2v = bl2[lane];
  float wfcr[64];
  const float* W = Wfc + (size_t)nt*4096;
  #pragma unroll
  for (int h=0;h<64;h++) wfcr[h] = W[h*64 + lane];
  const float zmin = decf(mm[0]), zmax = decf(mm[1]);
  const float rmin = 0.1f*eluf(zmin);
  const float rmax = 0.9f + 0.1f*eluf(zmax);
  const float s2 = 2.0f/(rmax - rmin + 1e-5f);
  const int nrows = min(32, R - r0);
  float gx=0.f, gy=0.f;
  if (lane < nrows){
    const float2 gv = ((const float2*)g)[c_aggoff[nt] + r0 + lane];
    gx = gv.x; gy = gv.y;
  }
  for (int r=0; r<nrows; r++){
    const float g0 = __uint_as_float(__builtin_amdgcn_readlane(__float_as_uint(gx), r));
    const float g1 = __uint_as_float(__builtin_amdgcn_readlane(__float_as_uint(gy), r));
    const float z = fmaf(g0, wl0, fmaf(g1, wl1, blv));
    const float nrm = fmaf(eluf(z) - rmin, s2, -1.0f);
    float acc = bfcv;
    #pragma unroll
    for (int h=0;h<64;h++){
      float nh = __uint_as_float(__builtin_amdgcn_readlane(__float_as_uint(nrm), h));
      acc = fmaf(nh, wfcr[h], acc);
    }
    float bv = eluf(acc);
    float sgm = bv;
    sgm += __shfl_xor(sgm,16);
    sgm += __shfl_xor(sgm,8);
    sgm += __shfl_xor(sgm,4);
    sgm += __shfl_xor(sgm,2);
    sgm += __shfl_xor(sgm,1);
    const float h0 = __uint_as_float(__builtin_amdgcn_readlane(__float_as_uint(sgm),0));
    const float h1 = __uint_as_float(__builtin_amdgcn_readlane(__float_as_uint(sgm),32));
    const float f = eluf(fmaf(h0, wl20, fmaf(h1, wl21, bl2v)));
    const size_t orow = (size_t)c_outoff[nt] + r0 + r;
    out[orow*64 + lane] = f;
    out[(orow + (size_t)R)*64 + lane] = f;
  }
}

extern "C" void kernel_launch(void* const* d_in, const int* in_sizes, int n_in,
                              void* d_out, int out_size, void* d_ws, size_t ws_size,
                              hipStream_t stream) {
  const float* xSB = (const float*)d_in[0];
  const float* cSB = (const float*)d_in[1];
  const float* xPQ = (const float*)d_in[2];
  const float* cPQ = (const float*)d_in[3];
  const float* xPV = (const float*)d_in[4];
  const float* cPV = (const float*)d_in[5];
  const float* xNB = (const float*)d_in[6];
  const float* cNB = (const float*)d_in[7];
  const int*   eidx = (const int*)d_in[8];
  const float* eattr= (const float*)d_in[9];
  const float* Wq = (const float*)d_in[10];
  const float* bq = (const float*)d_in[11];
  const float* Wk = (const float*)d_in[12];
  const float* bk = (const float*)d_in[13];
  const float* Wv = (const float*)d_in[14];
  const float* bv = (const float*)d_in[15];
  const float* We = (const float*)d_in[16];
  const float* be = (const float*)d_in[17];
  const float* Ws = (const float*)d_in[18];
  const float* bs = (const float*)d_in[19];
  const float* Wl = (const float*)d_in[20];
  const float* bl = (const float*)d_in[21];
  const float* Wfc= (const float*)d_in[22];
  const float* bfc= (const float*)d_in[23];
  const float* Wl2= (const float*)d_in[24];
  const float* bl2= (const float*)d_in[25];

  float* ws   = (float*)d_ws;
  float* xall = ws + 0;         // 488000 f
  float* par  = ws + 488000;    // 4800 f
  float* g    = ws + 492800;    // 960000 f
  unsigned* mm = (unsigned*)(ws + 1452800); // 2

  hipMemsetAsync(mm,   0xFF, 4, stream);  // encoded min identity
  hipMemsetAsync(mm+1, 0x00, 4, stream);  // encoded max identity

  k_build_x<<<(61000+255)/256, 256, 0, stream>>>(xSB,cSB,xPQ,cPQ,xPV,cPV,xNB,cNB, xall);
  k_params<<<30, 64, 0, stream>>>(Wq,bq,Wk,bk,Wv,bv,We,be,Ws,bs, par);
  k_fused<<<240, 1024, 0, stream>>>(eidx, eattr, xall, par, Wl, bl, g, mm);
  k_final<<<3751, 256, 0, stream>>>(g, mm, Wl, bl, Wfc, bfc, Wl2, bl2, (float*)d_out);
}